// Round 5
// baseline (132.803 us; speedup 1.0000x reference)
//
#include <hip/hip_runtime.h>

typedef __attribute__((ext_vector_type(8))) short short8;
typedef __attribute__((ext_vector_type(4))) float f32x4;
typedef unsigned short u16;
typedef unsigned int u32;

#define NNODES 65536
#define FDIM 128

__device__ __forceinline__ u16 f2bf(float f) {
    u32 u = __float_as_uint(f);
    u32 r = (u + 0x7fffu + ((u >> 16) & 1u)) >> 16;   // RNE
    return (u16)r;
}
__device__ __forceinline__ u32 pack2bf(float lo, float hi) {
    return ((u32)f2bf(hi) << 16) | f2bf(lo);
}

// ---------- rowptr via binary search over sorted edge_row ----------
__global__ void rowptr_kernel(const int* __restrict__ erow, int* __restrict__ rowptr,
                              int n, int e) {
    int r = blockIdx.x * blockDim.x + threadIdx.x;
    if (r > n) return;
    int lo = 0, hi = e;
    while (lo < hi) {
        int mid = (lo + hi) >> 1;
        if (erow[mid] < r) lo = mid + 1; else hi = mid;
    }
    rowptr[r] = lo;
}

// ---------- x fp32 -> bf16 ----------
__global__ void cvt_x_kernel(const float* __restrict__ x, u16* __restrict__ xb, int total4) {
    int i = blockIdx.x * blockDim.x + threadIdx.x;
    if (i >= total4) return;
    float4 v = reinterpret_cast<const float4*>(x)[i];
    uint2 p;
    p.x = pack2bf(v.x, v.y);
    p.y = pack2bf(v.z, v.w);
    reinterpret_cast<uint2*>(xb)[i] = p;
}

// ---------- weight fp32 [K][NC] -> bf16 transposed [NC][K] ----------
__global__ void cvt_wT_kernel(const float* __restrict__ w, u16* __restrict__ wt,
                              int K, int NC) {
    int idx = blockIdx.x * blockDim.x + threadIdx.x;
    if (idx >= K * NC) return;
    int n = idx / K, k = idx - n * K;
    wt[idx] = f2bf(w[k * NC + n]);
}

// ---------- SpMM v3: one wave per row, 8 edges in flight ----------
// lane = (slot = lane>>3 -> edge index mod 8, fg = lane&7 -> features
// fg*16..fg*16+15). One gather round covers deg<=8 (~60% of rows, avg=8);
// 8 independent 32B gathers in flight per wave. col/val of the next chunk
// prefetched past the current gather. 3-stage butterfly (8/16/32), then a
// coalesced 4B/lane packed-bf16 store.
__global__ void spmm_kernel(const u16* __restrict__ h, const int* __restrict__ rowptr,
                            const int* __restrict__ col, const float* __restrict__ val,
                            u16* __restrict__ y, int n) {
    int wid = (blockIdx.x * blockDim.x + threadIdx.x) >> 6;
    int lane = threadIdx.x & 63;
    if (wid >= n) return;
    const int slot = lane >> 3;
    const int fg = lane & 7;
    int s = rowptr[wid], e = rowptr[wid + 1];

    float acc[16];
#pragma unroll
    for (int j = 0; j < 16; ++j) acc[j] = 0.f;

    int i = s + slot;
    int c = 0; float v = 0.f;
    if (i < e) { c = col[i]; v = val[i]; }
    while (i < e) {
        int inext = i + 8;
        int cn = 0; float vn = 0.f;
        if (inext < e) { cn = col[inext]; vn = val[inext]; }   // prefetch next chunk
        const u16* hp = h + (size_t)c * FDIM + fg * 16;
        short8 h0 = *reinterpret_cast<const short8*>(hp);
        short8 h1 = *reinterpret_cast<const short8*>(hp + 8);
#pragma unroll
        for (int j = 0; j < 8; ++j) {
            acc[j]     = fmaf(v, __uint_as_float(((u32)(u16)h0[j]) << 16), acc[j]);
            acc[8 + j] = fmaf(v, __uint_as_float(((u32)(u16)h1[j]) << 16), acc[8 + j]);
        }
        i = inext; c = cn; v = vn;
    }

#pragma unroll
    for (int m = 8; m <= 32; m <<= 1)
#pragma unroll
        for (int j = 0; j < 16; ++j)
            acc[j] += __shfl_xor(acc[j], m, 64);

    float a0 = 0.f, a1 = 0.f;
#pragma unroll
    for (int ss = 0; ss < 8; ++ss)
        if (slot == ss) { a0 = acc[ss * 2]; a1 = acc[ss * 2 + 1]; }
    *reinterpret_cast<u32*>(y + (size_t)wid * FDIM + fg * 16 + slot * 2) = pack2bf(a0, a1);
}

// ---------- GEMM v3: LDS-staged weights, one 16-row chunk per wave ----------
// WT [NC][128] bf16 staged into LDS with padded stride 136 u16 (272B):
// conflict-free fragment ds_read_b128. Swapped-operand MFMA: lane (dn,kg)
// holds out[r0+dn][nt*16+kg*4+0..3] -> contiguous 8B/16B stores.
template<int NT, bool RELU, bool OUT_BF16>
__global__ __launch_bounds__(256, 4)
void gemm_kernel(const u16* __restrict__ A, const u16* __restrict__ WT,
                 void* __restrict__ out, int M) {
    constexpr int NC = NT * 16;
    constexpr int LSTR = 136;                 // u16: 128 data + 8 pad
    __shared__ u16 wlds[NC * LSTR];

    const int t = threadIdx.x;
    const int fr = t & 15;                    // 16B chunk within a 256B row
#pragma unroll
    for (int n = t >> 4; n < NC; n += 16)
        *reinterpret_cast<uint4*>(&wlds[n * LSTR + fr * 8]) =
            *reinterpret_cast<const uint4*>(&WT[(size_t)n * 128 + fr * 8]);
    __syncthreads();

    const int lane = t & 63;
    const int dn = lane & 15;
    const int kg = lane >> 4;
    const int r0 = (blockIdx.x * 4 + (t >> 6)) << 4;
    if (r0 >= M) return;

    f32x4 acc[NT];
#pragma unroll
    for (int nt = 0; nt < NT; ++nt) acc[nt] = (f32x4){0.f, 0.f, 0.f, 0.f};

#pragma unroll
    for (int s = 0; s < 4; ++s) {
        short8 a = *reinterpret_cast<const short8*>(
            &A[(size_t)(r0 + dn) * 128 + s * 32 + kg * 8]);
#pragma unroll
        for (int nt = 0; nt < NT; ++nt) {
            short8 b = *reinterpret_cast<const short8*>(
                &wlds[(nt * 16 + dn) * LSTR + s * 32 + kg * 8]);
            acc[nt] = __builtin_amdgcn_mfma_f32_16x16x32_bf16(b, a, acc[nt], 0, 0, 0);
        }
    }

    const int row = r0 + dn;
#pragma unroll
    for (int nt = 0; nt < NT; ++nt) {
        float v0 = acc[nt][0], v1 = acc[nt][1], v2 = acc[nt][2], v3 = acc[nt][3];
        if (RELU) {
            v0 = fmaxf(v0, 0.f); v1 = fmaxf(v1, 0.f);
            v2 = fmaxf(v2, 0.f); v3 = fmaxf(v3, 0.f);
        }
        if (OUT_BF16) {
            uint2 p; p.x = pack2bf(v0, v1); p.y = pack2bf(v2, v3);
            *reinterpret_cast<uint2*>(
                (u16*)out + (size_t)row * NC + nt * 16 + kg * 4) = p;
        } else {
            float4 p = make_float4(v0, v1, v2, v3);
            *reinterpret_cast<float4*>(
                (float*)out + (size_t)row * NC + nt * 16 + kg * 4) = p;
        }
    }
}

extern "C" void kernel_launch(void* const* d_in, const int* in_sizes, int n_in,
                              void* d_out, int out_size, void* d_ws, size_t ws_size,
                              hipStream_t stream) {
    const float* x    = (const float*)d_in[0];
    const float* w1   = (const float*)d_in[1];
    const float* w2   = (const float*)d_in[2];
    const float* w3   = (const float*)d_in[3];
    const int*   erow = (const int*)d_in[4];
    const int*   ecol = (const int*)d_in[5];
    const float* eval = (const float*)d_in[6];
    float* out = (float*)d_out;

    const int N = in_sizes[0] / FDIM;
    const int E = in_sizes[4];

    char* ws = (char*)d_ws;
    int* rowptr = (int*)ws;                                  // (N+1)*4
    u16* wt1 = (u16*)(ws + (512 << 10));                     // 32KB
    u16* wt2 = wt1 + 128 * 128;                              // 32KB
    u16* wt3 = wt2 + 128 * 128;                              // 16KB
    u16* ybuf = (u16*)(ws + (1 << 20));                      // 16MB bf16 [N][128]
    u16* hbuf = (u16*)(ws + (18u << 20));                    // 16MB bf16 [N][128]

    rowptr_kernel<<<(N + 1 + 255) / 256, 256, 0, stream>>>(erow, rowptr, N, E);
    cvt_wT_kernel<<<(128 * 128 + 255) / 256, 256, 0, stream>>>(w1, wt1, 128, 128);
    cvt_wT_kernel<<<(128 * 128 + 255) / 256, 256, 0, stream>>>(w2, wt2, 128, 128);
    cvt_wT_kernel<<<(64 * 128 + 255) / 256, 256, 0, stream>>>(w3, wt3, 128, 64);
    cvt_x_kernel<<<(N * FDIM / 4 + 255) / 256, 256, 0, stream>>>(x, hbuf, N * FDIM / 4);
    spmm_kernel<<<N / 4, 256, 0, stream>>>(hbuf, rowptr, ecol, eval, ybuf, N);
    gemm_kernel<8, true, true><<<N / 64, 256, 0, stream>>>(ybuf, wt1, hbuf, N);
    spmm_kernel<<<N / 4, 256, 0, stream>>>(hbuf, rowptr, ecol, eval, ybuf, N);
    gemm_kernel<8, true, true><<<N / 64, 256, 0, stream>>>(ybuf, wt2, hbuf, N);
    gemm_kernel<4, false, false><<<N / 64, 256, 0, stream>>>(hbuf, wt3, (void*)out, N);
}

// Round 6
// 122.656 us; speedup vs baseline: 1.0827x; 1.0827x over previous
//
#include <hip/hip_runtime.h>

typedef __attribute__((ext_vector_type(8))) short short8;
typedef __attribute__((ext_vector_type(4))) float f32x4;
typedef unsigned short u16;
typedef unsigned int u32;

#define NNODES 65536
#define FDIM 128

__device__ __forceinline__ u16 f2bf(float f) {
    u32 u = __float_as_uint(f);
    u32 r = (u + 0x7fffu + ((u >> 16) & 1u)) >> 16;   // RNE
    return (u16)r;
}
__device__ __forceinline__ u32 pack2bf(float lo, float hi) {
    return ((u32)f2bf(hi) << 16) | f2bf(lo);
}
__device__ __forceinline__ float bf2f(short s) {
    return __uint_as_float(((u32)(u16)s) << 16);
}

// ---------- rowptr via binary search over sorted edge_row ----------
__global__ void rowptr_kernel(const int* __restrict__ erow, int* __restrict__ rowptr,
                              int n, int e) {
    int r = blockIdx.x * blockDim.x + threadIdx.x;
    if (r > n) return;
    int lo = 0, hi = e;
    while (lo < hi) {
        int mid = (lo + hi) >> 1;
        if (erow[mid] < r) lo = mid + 1; else hi = mid;
    }
    rowptr[r] = lo;
}

// ---------- x fp32 -> bf16 ----------
__global__ void cvt_x_kernel(const float* __restrict__ x, u16* __restrict__ xb, int total4) {
    int i = blockIdx.x * blockDim.x + threadIdx.x;
    if (i >= total4) return;
    float4 v = reinterpret_cast<const float4*>(x)[i];
    uint2 p;
    p.x = pack2bf(v.x, v.y);
    p.y = pack2bf(v.z, v.w);
    reinterpret_cast<uint2*>(xb)[i] = p;
}

// ---------- weight fp32 [K][NC] -> bf16 transposed [NC][K] ----------
__global__ void cvt_wT_kernel(const float* __restrict__ w, u16* __restrict__ wt,
                              int K, int NC) {
    int idx = blockIdx.x * blockDim.x + threadIdx.x;
    if (idx >= K * NC) return;
    int n = idx / K, k = idx - n * K;
    wt[idx] = f2bf(w[k * NC + n]);
}

// ---------- SpMM v4: 4 rows/wave, 16 lanes/row, ILP-4 edge banks, NO shuffles ----------
// R4 post-mortem: the shuffle butterfly was the bottleneck (48 DS-ops/row ~= 30us
// of DS-pipe per spmm). Here each 16-lane group owns one row (fg = 8 features
// per lane) and walks its edge list 4-at-a-time into 4 independent register
// banks (4 gathers in flight), folded locally at the end. Zero cross-lane ops.
// Masked tail slots gather row 0 (L1-hot) with v=0. 16B/lane coalesced store.
__global__ __launch_bounds__(256, 8)
void spmm_kernel(const u16* __restrict__ h, const int* __restrict__ rowptr,
                 const int* __restrict__ col, const float* __restrict__ val,
                 u16* __restrict__ y, int n) {
    const int wid  = (blockIdx.x * blockDim.x + threadIdx.x) >> 6;
    const int lane = threadIdx.x & 63;
    const int grp  = lane >> 4;
    const int fg   = lane & 15;
    const int row  = wid * 4 + grp;
    if (row >= n) return;
    const int s = rowptr[row], e = rowptr[row + 1];

    float a0[8], a1[8], a2[8], a3[8];
#pragma unroll
    for (int j = 0; j < 8; ++j) { a0[j] = 0.f; a1[j] = 0.f; a2[j] = 0.f; a3[j] = 0.f; }

    const u16* hf = h + fg * 8;
    for (int base = s; base < e; base += 4) {
        const bool b1 = base + 1 < e, b2 = base + 2 < e, b3 = base + 3 < e;
        int   c0 = col[base];              float v0 = val[base];
        int   c1 = b1 ? col[base + 1] : 0; float v1 = b1 ? val[base + 1] : 0.f;
        int   c2 = b2 ? col[base + 2] : 0; float v2 = b2 ? val[base + 2] : 0.f;
        int   c3 = b3 ? col[base + 3] : 0; float v3 = b3 ? val[base + 3] : 0.f;
        short8 g0 = *reinterpret_cast<const short8*>(hf + (size_t)c0 * FDIM);
        short8 g1 = *reinterpret_cast<const short8*>(hf + (size_t)c1 * FDIM);
        short8 g2 = *reinterpret_cast<const short8*>(hf + (size_t)c2 * FDIM);
        short8 g3 = *reinterpret_cast<const short8*>(hf + (size_t)c3 * FDIM);
#pragma unroll
        for (int j = 0; j < 8; ++j) {
            a0[j] = fmaf(v0, bf2f(g0[j]), a0[j]);
            a1[j] = fmaf(v1, bf2f(g1[j]), a1[j]);
            a2[j] = fmaf(v2, bf2f(g2[j]), a2[j]);
            a3[j] = fmaf(v3, bf2f(g3[j]), a3[j]);
        }
    }

    uint4 p;
    {
        float f0 = (a0[0] + a1[0]) + (a2[0] + a3[0]);
        float f1 = (a0[1] + a1[1]) + (a2[1] + a3[1]);
        float f2 = (a0[2] + a1[2]) + (a2[2] + a3[2]);
        float f3 = (a0[3] + a1[3]) + (a2[3] + a3[3]);
        float f4 = (a0[4] + a1[4]) + (a2[4] + a3[4]);
        float f5 = (a0[5] + a1[5]) + (a2[5] + a3[5]);
        float f6 = (a0[6] + a1[6]) + (a2[6] + a3[6]);
        float f7 = (a0[7] + a1[7]) + (a2[7] + a3[7]);
        p.x = pack2bf(f0, f1); p.y = pack2bf(f2, f3);
        p.z = pack2bf(f4, f5); p.w = pack2bf(f6, f7);
    }
    *reinterpret_cast<uint4*>(y + (size_t)row * FDIM + fg * 8) = p;
}

// ---------- GEMM v3: LDS-staged weights, one 16-row chunk per wave ----------
// WT [NC][128] bf16 staged into LDS with padded stride 136 u16 (272B):
// conflict-free fragment ds_read_b128. Swapped-operand MFMA: lane (dn,kg)
// holds out[r0+dn][nt*16+kg*4+0..3] -> contiguous 8B/16B stores.
template<int NT, bool RELU, bool OUT_BF16>
__global__ __launch_bounds__(256, 4)
void gemm_kernel(const u16* __restrict__ A, const u16* __restrict__ WT,
                 void* __restrict__ out, int M) {
    constexpr int NC = NT * 16;
    constexpr int LSTR = 136;                 // u16: 128 data + 8 pad
    __shared__ u16 wlds[NC * LSTR];

    const int t = threadIdx.x;
    const int fr = t & 15;                    // 16B chunk within a 256B row
#pragma unroll
    for (int n = t >> 4; n < NC; n += 16)
        *reinterpret_cast<uint4*>(&wlds[n * LSTR + fr * 8]) =
            *reinterpret_cast<const uint4*>(&WT[(size_t)n * 128 + fr * 8]);
    __syncthreads();

    const int lane = t & 63;
    const int dn = lane & 15;
    const int kg = lane >> 4;
    const int r0 = (blockIdx.x * 4 + (t >> 6)) << 4;
    if (r0 >= M) return;

    f32x4 acc[NT];
#pragma unroll
    for (int nt = 0; nt < NT; ++nt) acc[nt] = (f32x4){0.f, 0.f, 0.f, 0.f};

#pragma unroll
    for (int s = 0; s < 4; ++s) {
        short8 a = *reinterpret_cast<const short8*>(
            &A[(size_t)(r0 + dn) * 128 + s * 32 + kg * 8]);
#pragma unroll
        for (int nt = 0; nt < NT; ++nt) {
            short8 b = *reinterpret_cast<const short8*>(
                &wlds[(nt * 16 + dn) * LSTR + s * 32 + kg * 8]);
            acc[nt] = __builtin_amdgcn_mfma_f32_16x16x32_bf16(b, a, acc[nt], 0, 0, 0);
        }
    }

    const int row = r0 + dn;
#pragma unroll
    for (int nt = 0; nt < NT; ++nt) {
        float v0 = acc[nt][0], v1 = acc[nt][1], v2 = acc[nt][2], v3 = acc[nt][3];
        if (RELU) {
            v0 = fmaxf(v0, 0.f); v1 = fmaxf(v1, 0.f);
            v2 = fmaxf(v2, 0.f); v3 = fmaxf(v3, 0.f);
        }
        if (OUT_BF16) {
            uint2 p; p.x = pack2bf(v0, v1); p.y = pack2bf(v2, v3);
            *reinterpret_cast<uint2*>(
                (u16*)out + (size_t)row * NC + nt * 16 + kg * 4) = p;
        } else {
            float4 p = make_float4(v0, v1, v2, v3);
            *reinterpret_cast<float4*>(
                (float*)out + (size_t)row * NC + nt * 16 + kg * 4) = p;
        }
    }
}

extern "C" void kernel_launch(void* const* d_in, const int* in_sizes, int n_in,
                              void* d_out, int out_size, void* d_ws, size_t ws_size,
                              hipStream_t stream) {
    const float* x    = (const float*)d_in[0];
    const float* w1   = (const float*)d_in[1];
    const float* w2   = (const float*)d_in[2];
    const float* w3   = (const float*)d_in[3];
    const int*   erow = (const int*)d_in[4];
    const int*   ecol = (const int*)d_in[5];
    const float* eval = (const float*)d_in[6];
    float* out = (float*)d_out;

    const int N = in_sizes[0] / FDIM;
    const int E = in_sizes[4];

    char* ws = (char*)d_ws;
    int* rowptr = (int*)ws;                                  // (N+1)*4
    u16* wt1 = (u16*)(ws + (512 << 10));                     // 32KB
    u16* wt2 = wt1 + 128 * 128;                              // 32KB
    u16* wt3 = wt2 + 128 * 128;                              // 16KB
    u16* ybuf = (u16*)(ws + (1 << 20));                      // 16MB bf16 [N][128]
    u16* hbuf = (u16*)(ws + (18u << 20));                    // 16MB bf16 [N][128]

    rowptr_kernel<<<(N + 1 + 255) / 256, 256, 0, stream>>>(erow, rowptr, N, E);
    cvt_wT_kernel<<<(128 * 128 + 255) / 256, 256, 0, stream>>>(w1, wt1, 128, 128);
    cvt_wT_kernel<<<(128 * 128 + 255) / 256, 256, 0, stream>>>(w2, wt2, 128, 128);
    cvt_wT_kernel<<<(64 * 128 + 255) / 256, 256, 0, stream>>>(w3, wt3, 128, 64);
    cvt_x_kernel<<<(N * FDIM / 4 + 255) / 256, 256, 0, stream>>>(x, hbuf, N * FDIM / 4);
    spmm_kernel<<<N / 16, 256, 0, stream>>>(hbuf, rowptr, ecol, eval, ybuf, N);
    gemm_kernel<8, true, true><<<N / 64, 256, 0, stream>>>(ybuf, wt1, hbuf, N);
    spmm_kernel<<<N / 16, 256, 0, stream>>>(hbuf, rowptr, ecol, eval, ybuf, N);
    gemm_kernel<8, true, true><<<N / 64, 256, 0, stream>>>(ybuf, wt2, hbuf, N);
    gemm_kernel<4, false, false><<<N / 64, 256, 0, stream>>>(hbuf, wt3, (void*)out, N);
}

// Round 7
// 104.638 us; speedup vs baseline: 1.2692x; 1.1722x over previous
//
#include <hip/hip_runtime.h>

typedef __attribute__((ext_vector_type(8))) short short8;
typedef __attribute__((ext_vector_type(4))) float f32x4;
typedef unsigned short u16;
typedef unsigned int u32;

#define NNODES 65536
#define FDIM 128

__device__ __forceinline__ u16 f2bf(float f) {
    u32 u = __float_as_uint(f);
    u32 r = (u + 0x7fffu + ((u >> 16) & 1u)) >> 16;   // RNE
    return (u16)r;
}
__device__ __forceinline__ u32 pack2bf(float lo, float hi) {
    return ((u32)f2bf(hi) << 16) | f2bf(lo);
}
__device__ __forceinline__ float bf2f(short s) {
    return __uint_as_float(((u32)(u16)s) << 16);
}

// ---------- rowptr via binary search over sorted edge_row ----------
__global__ void rowptr_kernel(const int* __restrict__ erow, int* __restrict__ rowptr,
                              int n, int e) {
    int r = blockIdx.x * blockDim.x + threadIdx.x;
    if (r > n) return;
    int lo = 0, hi = e;
    while (lo < hi) {
        int mid = (lo + hi) >> 1;
        if (erow[mid] < r) lo = mid + 1; else hi = mid;
    }
    rowptr[r] = lo;
}

// ---------- x fp32 -> bf16 ----------
__global__ void cvt_x_kernel(const float* __restrict__ x, u16* __restrict__ xb, int total4) {
    int i = blockIdx.x * blockDim.x + threadIdx.x;
    if (i >= total4) return;
    float4 v = reinterpret_cast<const float4*>(x)[i];
    uint2 p;
    p.x = pack2bf(v.x, v.y);
    p.y = pack2bf(v.z, v.w);
    reinterpret_cast<uint2*>(xb)[i] = p;
}

// ---------- weight fp32 [K][NC] -> bf16 transposed [NC][K] ----------
__global__ void cvt_wT_kernel(const float* __restrict__ w, u16* __restrict__ wt,
                              int K, int NC) {
    int idx = blockIdx.x * blockDim.x + threadIdx.x;
    if (idx >= K * NC) return;
    int n = idx / K, k = idx - n * K;
    wt[idx] = f2bf(w[k * NC + n]);
}

// ---------- SpMM (measured-best 4-slot butterfly, R3 config) + deeper prefetch ----------
// 1 row/wave; slot=lane>>4 covers edges i = s+slot+4k; fg=lane&15 covers 8
// features. Both gather rounds' col/val are loaded BEFORE the first gather and
// the two 256B gathers issue back-to-back (removes one dependent meta-load
// stage from the per-row serial chain). Inactive slots gather row 0 with v=0.
// 2-stage butterfly (16 shuffles/row) + coalesced 4B/lane packed store.
__global__ __launch_bounds__(256, 8)
void spmm_kernel(const u16* __restrict__ h, const int* __restrict__ rowptr,
                 const int* __restrict__ col, const float* __restrict__ val,
                 u16* __restrict__ y, int n) {
    int wid = (blockIdx.x * blockDim.x + threadIdx.x) >> 6;
    int lane = threadIdx.x & 63;
    if (wid >= n) return;
    const int slot = lane >> 4;
    const int fg = lane & 15;
    int s = rowptr[wid], e = rowptr[wid + 1];

    float acc[8];
#pragma unroll
    for (int j = 0; j < 8; ++j) acc[j] = 0.f;

    int i = s + slot;
    int c0 = 0, c1 = 0; float v0 = 0.f, v1 = 0.f;
    if (i < e)     { c0 = col[i];     v0 = val[i]; }
    if (i + 4 < e) { c1 = col[i + 4]; v1 = val[i + 4]; }

    while (i < e) {
        short8 g0 = *reinterpret_cast<const short8*>(h + (size_t)c0 * FDIM + fg * 8);
        short8 g1 = *reinterpret_cast<const short8*>(h + (size_t)c1 * FDIM + fg * 8);
        int c2 = 0, c3 = 0; float v2 = 0.f, v3 = 0.f;
        if (i + 8 < e)  { c2 = col[i + 8];  v2 = val[i + 8]; }
        if (i + 12 < e) { c3 = col[i + 12]; v3 = val[i + 12]; }
#pragma unroll
        for (int j = 0; j < 8; ++j) acc[j] = fmaf(v0, bf2f(g0[j]), acc[j]);
#pragma unroll
        for (int j = 0; j < 8; ++j) acc[j] = fmaf(v1, bf2f(g1[j]), acc[j]);
        c0 = c2; v0 = v2; c1 = c3; v1 = v3;
        i += 8;
    }

#pragma unroll
    for (int m = 16; m <= 32; m <<= 1)
#pragma unroll
        for (int j = 0; j < 8; ++j)
            acc[j] += __shfl_xor(acc[j], m, 64);

    float a0 = 0.f, a1 = 0.f;
#pragma unroll
    for (int ss = 0; ss < 4; ++ss)
        if (slot == ss) { a0 = acc[ss * 2]; a1 = acc[ss * 2 + 1]; }
    *reinterpret_cast<u32*>(y + (size_t)wid * FDIM + fg * 8 + slot * 2) = pack2bf(a0, a1);
}

// ---------- GEMM v3: LDS-staged weights, one 16-row chunk per wave ----------
template<int NT, bool RELU, bool OUT_BF16>
__global__ __launch_bounds__(256, 4)
void gemm_kernel(const u16* __restrict__ A, const u16* __restrict__ WT,
                 void* __restrict__ out, int M) {
    constexpr int NC = NT * 16;
    constexpr int LSTR = 136;                 // u16: 128 data + 8 pad
    __shared__ u16 wlds[NC * LSTR];

    const int t = threadIdx.x;
    const int fr = t & 15;
#pragma unroll
    for (int n = t >> 4; n < NC; n += 16)
        *reinterpret_cast<uint4*>(&wlds[n * LSTR + fr * 8]) =
            *reinterpret_cast<const uint4*>(&WT[(size_t)n * 128 + fr * 8]);
    __syncthreads();

    const int lane = t & 63;
    const int dn = lane & 15;
    const int kg = lane >> 4;
    const int r0 = (blockIdx.x * 4 + (t >> 6)) << 4;
    if (r0 >= M) return;

    f32x4 acc[NT];
#pragma unroll
    for (int nt = 0; nt < NT; ++nt) acc[nt] = (f32x4){0.f, 0.f, 0.f, 0.f};

#pragma unroll
    for (int s = 0; s < 4; ++s) {
        short8 a = *reinterpret_cast<const short8*>(
            &A[(size_t)(r0 + dn) * 128 + s * 32 + kg * 8]);
#pragma unroll
        for (int nt = 0; nt < NT; ++nt) {
            short8 b = *reinterpret_cast<const short8*>(
                &wlds[(nt * 16 + dn) * LSTR + s * 32 + kg * 8]);
            acc[nt] = __builtin_amdgcn_mfma_f32_16x16x32_bf16(b, a, acc[nt], 0, 0, 0);
        }
    }

    const int row = r0 + dn;
#pragma unroll
    for (int nt = 0; nt < NT; ++nt) {
        float v0 = acc[nt][0], v1 = acc[nt][1], v2 = acc[nt][2], v3 = acc[nt][3];
        if (RELU) {
            v0 = fmaxf(v0, 0.f); v1 = fmaxf(v1, 0.f);
            v2 = fmaxf(v2, 0.f); v3 = fmaxf(v3, 0.f);
        }
        if (OUT_BF16) {
            uint2 p; p.x = pack2bf(v0, v1); p.y = pack2bf(v2, v3);
            *reinterpret_cast<uint2*>(
                (u16*)out + (size_t)row * NC + nt * 16 + kg * 4) = p;
        } else {
            float4 p = make_float4(v0, v1, v2, v3);
            *reinterpret_cast<float4*>(
                (float*)out + (size_t)row * NC + nt * 16 + kg * 4) = p;
        }
    }
}

// ---------- Fused GEMM2+GEMM3: out = relu(Y @ W2) @ W3, no h2 round-trip ----------
// Per wave: compute 16x128 relu'd h2 tile (W2 from LDS, stride-136), dump it to
// a PRIVATE per-wave LDS region (no barrier; same-wave lgkmcnt ordering), read
// it back as the A-operand fragments of the W3 MFMA. W3 fragments are held in
// registers (64 VGPR, loaded from global once, in flight during gemm2).
__global__ __launch_bounds__(256, 2)
void gemm23_kernel(const u16* __restrict__ A, const u16* __restrict__ WT2,
                   const u16* __restrict__ WT3, float* __restrict__ out, int M) {
    constexpr int LSTR = 136;
    __shared__ u16 w2l[128 * LSTR];           // 34816 B
    __shared__ u16 h2l[4][16 * LSTR];         // 17408 B (4.3KB per wave, private)

    const int t = threadIdx.x;
    const int fr = t & 15;
#pragma unroll
    for (int n = t >> 4; n < 128; n += 16)
        *reinterpret_cast<uint4*>(&w2l[n * LSTR + fr * 8]) =
            *reinterpret_cast<const uint4*>(&WT2[(size_t)n * 128 + fr * 8]);

    const int wave = t >> 6;
    const int lane = t & 63;
    const int dn = lane & 15;
    const int kg = lane >> 4;

    // W3 fragments in registers: bw3[nt][s] = WT3[(nt*16+dn)][s*32+kg*8 ..+7]
    short8 bw3[4][4];
#pragma unroll
    for (int nt = 0; nt < 4; ++nt)
#pragma unroll
        for (int s = 0; s < 4; ++s)
            bw3[nt][s] = *reinterpret_cast<const short8*>(
                &WT3[(size_t)(nt * 16 + dn) * 128 + s * 32 + kg * 8]);

    __syncthreads();

    const int r0 = (blockIdx.x * 4 + wave) << 4;
    if (r0 >= M) return;

    // ---- gemm2: acc2 = Y(16x128) @ W2 ----
    f32x4 acc2[8];
#pragma unroll
    for (int nt = 0; nt < 8; ++nt) acc2[nt] = (f32x4){0.f, 0.f, 0.f, 0.f};
#pragma unroll
    for (int s = 0; s < 4; ++s) {
        short8 a = *reinterpret_cast<const short8*>(
            &A[(size_t)(r0 + dn) * 128 + s * 32 + kg * 8]);
#pragma unroll
        for (int nt = 0; nt < 8; ++nt) {
            short8 b = *reinterpret_cast<const short8*>(
                &w2l[(nt * 16 + dn) * LSTR + s * 32 + kg * 8]);
            acc2[nt] = __builtin_amdgcn_mfma_f32_16x16x32_bf16(b, a, acc2[nt], 0, 0, 0);
        }
    }

    // ---- relu + pack -> private LDS tile [row dn][col nt*16+kg*4 ..+3] ----
    u16* my = h2l[wave];
#pragma unroll
    for (int nt = 0; nt < 8; ++nt) {
        float v0 = fmaxf(acc2[nt][0], 0.f), v1 = fmaxf(acc2[nt][1], 0.f);
        float v2 = fmaxf(acc2[nt][2], 0.f), v3 = fmaxf(acc2[nt][3], 0.f);
        uint2 p; p.x = pack2bf(v0, v1); p.y = pack2bf(v2, v3);
        *reinterpret_cast<uint2*>(&my[dn * LSTR + nt * 16 + kg * 4]) = p;
    }

    // ---- gemm3: out = h2(16x128) @ W3 (A-frags re-read from private LDS) ----
    f32x4 acc3[4];
#pragma unroll
    for (int nt = 0; nt < 4; ++nt) acc3[nt] = (f32x4){0.f, 0.f, 0.f, 0.f};
#pragma unroll
    for (int s = 0; s < 4; ++s) {
        short8 a = *reinterpret_cast<const short8*>(
            &my[dn * LSTR + s * 32 + kg * 8]);
#pragma unroll
        for (int nt = 0; nt < 4; ++nt)
            acc3[nt] = __builtin_amdgcn_mfma_f32_16x16x32_bf16(bw3[nt][s], a, acc3[nt], 0, 0, 0);
    }

    const int row = r0 + dn;
#pragma unroll
    for (int nt = 0; nt < 4; ++nt)
        *reinterpret_cast<float4*>(out + (size_t)row * 64 + nt * 16 + kg * 4) =
            make_float4(acc3[nt][0], acc3[nt][1], acc3[nt][2], acc3[nt][3]);
}

extern "C" void kernel_launch(void* const* d_in, const int* in_sizes, int n_in,
                              void* d_out, int out_size, void* d_ws, size_t ws_size,
                              hipStream_t stream) {
    const float* x    = (const float*)d_in[0];
    const float* w1   = (const float*)d_in[1];
    const float* w2   = (const float*)d_in[2];
    const float* w3   = (const float*)d_in[3];
    const int*   erow = (const int*)d_in[4];
    const int*   ecol = (const int*)d_in[5];
    const float* eval = (const float*)d_in[6];
    float* out = (float*)d_out;

    const int N = in_sizes[0] / FDIM;
    const int E = in_sizes[4];

    char* ws = (char*)d_ws;
    int* rowptr = (int*)ws;                                  // (N+1)*4
    u16* wt1 = (u16*)(ws + (512 << 10));                     // 32KB
    u16* wt2 = wt1 + 128 * 128;                              // 32KB
    u16* wt3 = wt2 + 128 * 128;                              // 16KB
    u16* ybuf = (u16*)(ws + (1 << 20));                      // 16MB bf16 [N][128]
    u16* hbuf = (u16*)(ws + (18u << 20));                    // 16MB bf16 [N][128]

    rowptr_kernel<<<(N + 1 + 255) / 256, 256, 0, stream>>>(erow, rowptr, N, E);
    cvt_wT_kernel<<<(128 * 128 + 255) / 256, 256, 0, stream>>>(w1, wt1, 128, 128);
    cvt_wT_kernel<<<(128 * 128 + 255) / 256, 256, 0, stream>>>(w2, wt2, 128, 128);
    cvt_wT_kernel<<<(64 * 128 + 255) / 256, 256, 0, stream>>>(w3, wt3, 128, 64);
    cvt_x_kernel<<<(N * FDIM / 4 + 255) / 256, 256, 0, stream>>>(x, hbuf, N * FDIM / 4);
    spmm_kernel<<<N / 4, 256, 0, stream>>>(hbuf, rowptr, ecol, eval, ybuf, N);
    gemm_kernel<8, true, true><<<N / 64, 256, 0, stream>>>(ybuf, wt1, hbuf, N);
    spmm_kernel<<<N / 4, 256, 0, stream>>>(hbuf, rowptr, ecol, eval, ybuf, N);
    gemm23_kernel<<<N / 64, 256, 0, stream>>>(ybuf, wt2, wt3, out, N);
}

// Round 8
// 95.424 us; speedup vs baseline: 1.3917x; 1.0966x over previous
//
#include <hip/hip_runtime.h>

typedef __attribute__((ext_vector_type(8))) short short8;
typedef __attribute__((ext_vector_type(4))) float f32x4;
typedef unsigned short u16;
typedef unsigned int u32;

#define NNODES 65536
#define FDIM 128

__device__ __forceinline__ u16 f2bf(float f) {
    u32 u = __float_as_uint(f);
    u32 r = (u + 0x7fffu + ((u >> 16) & 1u)) >> 16;   // RNE
    return (u16)r;
}
__device__ __forceinline__ u32 pack2bf(float lo, float hi) {
    return ((u32)f2bf(hi) << 16) | f2bf(lo);
}
__device__ __forceinline__ float bf2f(short s) {
    return __uint_as_float(((u32)(u16)s) << 16);
}

// ---------- fused prep: rowptr + wT casts + x cast, partitioned by blockIdx ----------
// blocks [0,257): rowptr binary search; [257,321): w1; [321,385): w2;
// [385,417): w3; [417,8609): x -> bf16. Saves 4 kernel launches.
__global__ void prep_kernel(const int* __restrict__ erow, int* __restrict__ rowptr,
                            const float* __restrict__ w1, u16* __restrict__ wt1,
                            const float* __restrict__ w2, u16* __restrict__ wt2,
                            const float* __restrict__ w3, u16* __restrict__ wt3,
                            const float* __restrict__ x, u16* __restrict__ xb,
                            int n, int e) {
    const int b = blockIdx.x;
    const int tid = threadIdx.x;
    if (b < 257) {                               // rowptr
        int r = b * 256 + tid;
        if (r > n) return;
        int lo = 0, hi = e;
        while (lo < hi) {
            int mid = (lo + hi) >> 1;
            if (erow[mid] < r) lo = mid + 1; else hi = mid;
        }
        rowptr[r] = lo;
    } else if (b < 417) {                        // weight transpose-cast
        const float* w; u16* wt; int idx;
        if (b < 321)      { w = w1; wt = wt1; idx = (b - 257) * 256 + tid; }
        else if (b < 385) { w = w2; wt = wt2; idx = (b - 321) * 256 + tid; }
        else              { w = w3; wt = wt3; idx = (b - 385) * 256 + tid; }
        const int K = 128;
        const int NC = (b < 385) ? 128 : 64;
        if (idx >= K * NC) return;
        int nn = idx / K, k = idx - nn * K;
        wt[idx] = f2bf(w[k * NC + nn]);
    } else {                                     // x -> bf16 (uint2 per thread)
        int i = (b - 417) * 256 + tid;
        if (i >= n * FDIM / 4) return;
        float4 v = reinterpret_cast<const float4*>(x)[i];
        uint2 p;
        p.x = pack2bf(v.x, v.y);
        p.y = pack2bf(v.z, v.w);
        reinterpret_cast<uint2*>(xb)[i] = p;
    }
}

// ---------- SpMM v5: 2 rows/wave, 4-slot butterfly, all first-round gathers upfront ----------
// slot=lane>>4 (edge index mod 4), fg=lane&15 (8 features). Both rows' meta is
// loaded and all 4 first-8-edge gathers are issued back-to-back before any fma
// (4 independent 256B gathers in flight/wave; 2x R6). Remainder meta (deg>8)
// prefetched before the first fmas. 16 shuffles/row butterfly, coalesced store.
__global__ __launch_bounds__(256, 6)
void spmm_kernel(const u16* __restrict__ h, const int* __restrict__ rowptr,
                 const int* __restrict__ col, const float* __restrict__ val,
                 u16* __restrict__ y, int n) {
    const int wid  = (blockIdx.x * blockDim.x + threadIdx.x) >> 6;
    const int lane = threadIdx.x & 63;
    const int rA = wid * 2;
    if (rA >= n) return;
    const int slot = lane >> 4;
    const int fg = lane & 15;

    const int sA = rowptr[rA], eA = rowptr[rA + 1], eB = rowptr[rA + 2];

    // --- meta for first 8 edges of both rows ---
    int iA = sA + slot;
    int c0A = 0, c1A = 0; float v0A = 0.f, v1A = 0.f;
    if (iA < eA)     { c0A = col[iA];     v0A = val[iA]; }
    if (iA + 4 < eA) { c1A = col[iA + 4]; v1A = val[iA + 4]; }
    int iB = eA + slot;
    int c0B = 0, c1B = 0; float v0B = 0.f, v1B = 0.f;
    if (iB < eB)     { c0B = col[iB];     v0B = val[iB]; }
    if (iB + 4 < eB) { c1B = col[iB + 4]; v1B = val[iB + 4]; }

    // --- issue all 4 gathers back-to-back ---
    const u16* hf = h + fg * 8;
    short8 g0A = *reinterpret_cast<const short8*>(hf + (size_t)c0A * FDIM);
    short8 g1A = *reinterpret_cast<const short8*>(hf + (size_t)c1A * FDIM);
    short8 g0B = *reinterpret_cast<const short8*>(hf + (size_t)c0B * FDIM);
    short8 g1B = *reinterpret_cast<const short8*>(hf + (size_t)c1B * FDIM);

    // --- prefetch remainder meta early (overlaps with fmas below) ---
    int jA = iA + 8;
    int c2A = 0, c3A = 0; float v2A = 0.f, v3A = 0.f;
    if (jA < eA)     { c2A = col[jA];     v2A = val[jA]; }
    if (jA + 4 < eA) { c3A = col[jA + 4]; v3A = val[jA + 4]; }
    int jB = iB + 8;
    int c2B = 0, c3B = 0; float v2B = 0.f, v3B = 0.f;
    if (jB < eB)     { c2B = col[jB];     v2B = val[jB]; }
    if (jB + 4 < eB) { c3B = col[jB + 4]; v3B = val[jB + 4]; }

    float accA[8], accB[8];
#pragma unroll
    for (int j = 0; j < 8; ++j) { accA[j] = 0.f; accB[j] = 0.f; }

#pragma unroll
    for (int j = 0; j < 8; ++j) accA[j] = fmaf(v0A, bf2f(g0A[j]), accA[j]);
#pragma unroll
    for (int j = 0; j < 8; ++j) accA[j] = fmaf(v1A, bf2f(g1A[j]), accA[j]);
#pragma unroll
    for (int j = 0; j < 8; ++j) accB[j] = fmaf(v0B, bf2f(g0B[j]), accB[j]);
#pragma unroll
    for (int j = 0; j < 8; ++j) accB[j] = fmaf(v1B, bf2f(g1B[j]), accB[j]);

    // --- remainder rounds (deg > 8), row A then row B ---
    while (jA < eA) {
        short8 g0 = *reinterpret_cast<const short8*>(hf + (size_t)c2A * FDIM);
        short8 g1 = *reinterpret_cast<const short8*>(hf + (size_t)c3A * FDIM);
        float v0 = v2A, v1 = v3A;
        jA += 8;
        c2A = 0; c3A = 0; v2A = 0.f; v3A = 0.f;
        if (jA < eA)     { c2A = col[jA];     v2A = val[jA]; }
        if (jA + 4 < eA) { c3A = col[jA + 4]; v3A = val[jA + 4]; }
#pragma unroll
        for (int j = 0; j < 8; ++j) accA[j] = fmaf(v0, bf2f(g0[j]), accA[j]);
#pragma unroll
        for (int j = 0; j < 8; ++j) accA[j] = fmaf(v1, bf2f(g1[j]), accA[j]);
    }
    while (jB < eB) {
        short8 g0 = *reinterpret_cast<const short8*>(hf + (size_t)c2B * FDIM);
        short8 g1 = *reinterpret_cast<const short8*>(hf + (size_t)c3B * FDIM);
        float v0 = v2B, v1 = v3B;
        jB += 8;
        c2B = 0; c3B = 0; v2B = 0.f; v3B = 0.f;
        if (jB < eB)     { c2B = col[jB];     v2B = val[jB]; }
        if (jB + 4 < eB) { c3B = col[jB + 4]; v3B = val[jB + 4]; }
#pragma unroll
        for (int j = 0; j < 8; ++j) accB[j] = fmaf(v0, bf2f(g0[j]), accB[j]);
#pragma unroll
        for (int j = 0; j < 8; ++j) accB[j] = fmaf(v1, bf2f(g1[j]), accB[j]);
    }

    // --- butterfly across slots (full sum in all lanes), both rows ---
#pragma unroll
    for (int m = 16; m <= 32; m <<= 1) {
#pragma unroll
        for (int j = 0; j < 8; ++j) {
            accA[j] += __shfl_xor(accA[j], m, 64);
            accB[j] += __shfl_xor(accB[j], m, 64);
        }
    }

    float a0 = 0.f, a1 = 0.f, b0 = 0.f, b1 = 0.f;
#pragma unroll
    for (int ss = 0; ss < 4; ++ss)
        if (slot == ss) {
            a0 = accA[ss * 2]; a1 = accA[ss * 2 + 1];
            b0 = accB[ss * 2]; b1 = accB[ss * 2 + 1];
        }
    *reinterpret_cast<u32*>(y + (size_t)rA * FDIM + fg * 8 + slot * 2) = pack2bf(a0, a1);
    *reinterpret_cast<u32*>(y + (size_t)(rA + 1) * FDIM + fg * 8 + slot * 2) = pack2bf(b0, b1);
}

// ---------- GEMM v3: LDS-staged weights, one 16-row chunk per wave ----------
template<int NT, bool RELU, bool OUT_BF16>
__global__ __launch_bounds__(256, 4)
void gemm_kernel(const u16* __restrict__ A, const u16* __restrict__ WT,
                 void* __restrict__ out, int M) {
    constexpr int NC = NT * 16;
    constexpr int LSTR = 136;                 // u16: 128 data + 8 pad
    __shared__ u16 wlds[NC * LSTR];

    const int t = threadIdx.x;
    const int fr = t & 15;
#pragma unroll
    for (int n = t >> 4; n < NC; n += 16)
        *reinterpret_cast<uint4*>(&wlds[n * LSTR + fr * 8]) =
            *reinterpret_cast<const uint4*>(&WT[(size_t)n * 128 + fr * 8]);
    __syncthreads();

    const int lane = t & 63;
    const int dn = lane & 15;
    const int kg = lane >> 4;
    const int r0 = (blockIdx.x * 4 + (t >> 6)) << 4;
    if (r0 >= M) return;

    f32x4 acc[NT];
#pragma unroll
    for (int nt = 0; nt < NT; ++nt) acc[nt] = (f32x4){0.f, 0.f, 0.f, 0.f};

#pragma unroll
    for (int s = 0; s < 4; ++s) {
        short8 a = *reinterpret_cast<const short8*>(
            &A[(size_t)(r0 + dn) * 128 + s * 32 + kg * 8]);
#pragma unroll
        for (int nt = 0; nt < NT; ++nt) {
            short8 b = *reinterpret_cast<const short8*>(
                &wlds[(nt * 16 + dn) * LSTR + s * 32 + kg * 8]);
            acc[nt] = __builtin_amdgcn_mfma_f32_16x16x32_bf16(b, a, acc[nt], 0, 0, 0);
        }
    }

    const int row = r0 + dn;
#pragma unroll
    for (int nt = 0; nt < NT; ++nt) {
        float v0 = acc[nt][0], v1 = acc[nt][1], v2 = acc[nt][2], v3 = acc[nt][3];
        if (RELU) {
            v0 = fmaxf(v0, 0.f); v1 = fmaxf(v1, 0.f);
            v2 = fmaxf(v2, 0.f); v3 = fmaxf(v3, 0.f);
        }
        if (OUT_BF16) {
            uint2 p; p.x = pack2bf(v0, v1); p.y = pack2bf(v2, v3);
            *reinterpret_cast<uint2*>(
                (u16*)out + (size_t)row * NC + nt * 16 + kg * 4) = p;
        } else {
            float4 p = make_float4(v0, v1, v2, v3);
            *reinterpret_cast<float4*>(
                (float*)out + (size_t)row * NC + nt * 16 + kg * 4) = p;
        }
    }
}

// ---------- Fused GEMM2+GEMM3: out = relu(Y @ W2) @ W3, no h2 round-trip ----------
__global__ __launch_bounds__(256, 2)
void gemm23_kernel(const u16* __restrict__ A, const u16* __restrict__ WT2,
                   const u16* __restrict__ WT3, float* __restrict__ out, int M) {
    constexpr int LSTR = 136;
    __shared__ u16 w2l[128 * LSTR];           // 34816 B
    __shared__ u16 h2l[4][16 * LSTR];         // 17408 B (4.3KB per wave, private)

    const int t = threadIdx.x;
    const int fr = t & 15;
#pragma unroll
    for (int n = t >> 4; n < 128; n += 16)
        *reinterpret_cast<uint4*>(&w2l[n * LSTR + fr * 8]) =
            *reinterpret_cast<const uint4*>(&WT2[(size_t)n * 128 + fr * 8]);

    const int wave = t >> 6;
    const int lane = t & 63;
    const int dn = lane & 15;
    const int kg = lane >> 4;

    short8 bw3[4][4];
#pragma unroll
    for (int nt = 0; nt < 4; ++nt)
#pragma unroll
        for (int s = 0; s < 4; ++s)
            bw3[nt][s] = *reinterpret_cast<const short8*>(
                &WT3[(size_t)(nt * 16 + dn) * 128 + s * 32 + kg * 8]);

    __syncthreads();

    const int r0 = (blockIdx.x * 4 + wave) << 4;
    if (r0 >= M) return;

    f32x4 acc2[8];
#pragma unroll
    for (int nt = 0; nt < 8; ++nt) acc2[nt] = (f32x4){0.f, 0.f, 0.f, 0.f};
#pragma unroll
    for (int s = 0; s < 4; ++s) {
        short8 a = *reinterpret_cast<const short8*>(
            &A[(size_t)(r0 + dn) * 128 + s * 32 + kg * 8]);
#pragma unroll
        for (int nt = 0; nt < 8; ++nt) {
            short8 b = *reinterpret_cast<const short8*>(
                &w2l[(nt * 16 + dn) * LSTR + s * 32 + kg * 8]);
            acc2[nt] = __builtin_amdgcn_mfma_f32_16x16x32_bf16(b, a, acc2[nt], 0, 0, 0);
        }
    }

    u16* my = h2l[wave];
#pragma unroll
    for (int nt = 0; nt < 8; ++nt) {
        float v0 = fmaxf(acc2[nt][0], 0.f), v1 = fmaxf(acc2[nt][1], 0.f);
        float v2 = fmaxf(acc2[nt][2], 0.f), v3 = fmaxf(acc2[nt][3], 0.f);
        uint2 p; p.x = pack2bf(v0, v1); p.y = pack2bf(v2, v3);
        *reinterpret_cast<uint2*>(&my[dn * LSTR + nt * 16 + kg * 4]) = p;
    }

    f32x4 acc3[4];
#pragma unroll
    for (int nt = 0; nt < 4; ++nt) acc3[nt] = (f32x4){0.f, 0.f, 0.f, 0.f};
#pragma unroll
    for (int s = 0; s < 4; ++s) {
        short8 a = *reinterpret_cast<const short8*>(
            &my[dn * LSTR + s * 32 + kg * 8]);
#pragma unroll
        for (int nt = 0; nt < 4; ++nt)
            acc3[nt] = __builtin_amdgcn_mfma_f32_16x16x32_bf16(bw3[nt][s], a, acc3[nt], 0, 0, 0);
    }

    const int row = r0 + dn;
#pragma unroll
    for (int nt = 0; nt < 4; ++nt)
        *reinterpret_cast<float4*>(out + (size_t)row * 64 + nt * 16 + kg * 4) =
            make_float4(acc3[nt][0], acc3[nt][1], acc3[nt][2], acc3[nt][3]);
}

extern "C" void kernel_launch(void* const* d_in, const int* in_sizes, int n_in,
                              void* d_out, int out_size, void* d_ws, size_t ws_size,
                              hipStream_t stream) {
    const float* x    = (const float*)d_in[0];
    const float* w1   = (const float*)d_in[1];
    const float* w2   = (const float*)d_in[2];
    const float* w3   = (const float*)d_in[3];
    const int*   erow = (const int*)d_in[4];
    const int*   ecol = (const int*)d_in[5];
    const float* eval = (const float*)d_in[6];
    float* out = (float*)d_out;

    const int N = in_sizes[0] / FDIM;
    const int E = in_sizes[4];

    char* ws = (char*)d_ws;
    int* rowptr = (int*)ws;                                  // (N+1)*4
    u16* wt1 = (u16*)(ws + (512 << 10));                     // 32KB
    u16* wt2 = wt1 + 128 * 128;                              // 32KB
    u16* wt3 = wt2 + 128 * 128;                              // 16KB
    u16* ybuf = (u16*)(ws + (1 << 20));                      // 16MB bf16 [N][128]
    u16* hbuf = (u16*)(ws + (18u << 20));                    // 16MB bf16 [N][128]

    const int xblocks = N * FDIM / 4 / 256;                  // 8192
    prep_kernel<<<417 + xblocks, 256, 0, stream>>>(erow, rowptr, w1, wt1, w2, wt2,
                                                   w3, wt3, x, hbuf, N, E);
    spmm_kernel<<<N / 8, 256, 0, stream>>>(hbuf, rowptr, ecol, eval, ybuf, N);
    gemm_kernel<8, true, true><<<N / 64, 256, 0, stream>>>(ybuf, wt1, hbuf, N);
    spmm_kernel<<<N / 8, 256, 0, stream>>>(hbuf, rowptr, ecol, eval, ybuf, N);
    gemm23_kernel<<<N / 64, 256, 0, stream>>>(ybuf, wt2, wt3, out, N);
}